// Round 1
// 135.245 us; speedup vs baseline: 1.0204x; 1.0204x over previous
//
#include <hip/hip_runtime.h>
#include <math.h>

// Problem constants (fixed by reference): B=16, K=64, H=96, W=96
#define NB 16
#define NK 64
#define NH 96
#define NW 96
#define HW (NH * NW)          // 9216
#define PAIRS (NB * NK)       // 1024 maps per stack
#define HW4 (HW / 4)          // 2304 float4 per map
#define ITERS (HW4 / 256)     // 9 float4 per thread
#define MAP_ELEMS ((size_t)NB * NK * HW)   // 9437184

// Output layout (flat, return order):
//   Dk @0, tf_Dk @MAP_ELEMS, keypoint @2*MAP_ELEMS ([B,3K,2]=6144),
//   tf_keypoint, get_zeta ([B,K]=1024), tf_get_zeta
#define KP_BASE   ((size_t)2 * MAP_ELEMS)
#define KP_STACK  ((size_t)NB * 3 * NK * 2)    // 6144
#define ZETA_BASE (KP_BASE + 2 * KP_STACK)

// native clang vector (HIP float4 is a class — nontemporal builtin rejects it)
typedef float vfloat4 __attribute__((ext_vector_type(4)));

#define NEG_LOG2E (-1.44269504088896340736f)

__device__ __forceinline__ float hw_exp2(float x) {
#if __has_builtin(__builtin_amdgcn_exp2f)
    return __builtin_amdgcn_exp2f(x);
#else
    float r;
    asm volatile("v_exp_f32 %0, %1" : "=v"(r) : "v"(x));
    return r;
#endif
}

// sigmoid(x) = 1 / (1 + 2^(-x*log2 e)) — 3 VALU ops (mul, v_exp, add) + v_rcp.
// ~2-3 ulp. Per-element error cancels in the kx/zeta quotient (common bias
// cancels exactly; random part averages down by sqrt(9216)).
__device__ __forceinline__ float sigf(float x) {
    const float t = hw_exp2(x * NEG_LOG2E);
    return __builtin_amdgcn_rcpf(1.0f + t);
}

// Decode for one map given exact (double) sums. fp32 division + rint
// (half-to-even, matches jnp.round on fp32), trunc without fma contraction.
__device__ __forceinline__ void decode_one(
        double z, double kx, double ky,
        const float* __restrict__ src,
        float* __restrict__ kp,
        int k) {
#pragma clang fp contract(off)
    const float zf  = (float)z;
    const float kpx = rintf((float)kx / zf);
    const float kpy = rintf((float)ky / zf);

    const int wi = (int)kpx;
    const int hi = (int)kpy;
    const float d = sigf(src[hi * NW + wi]);

    const float tx = kpx * d;
    const float ty = kpy * d;
    const float k1x = truncf(kpx + tx), k1y = truncf(kpy + ty);
    const float k2x = truncf(kpx - tx), k2y = truncf(kpy - ty);

    kp[k * 2 + 0]            = kpx;  kp[k * 2 + 1]            = kpy;
    kp[(NK + k) * 2 + 0]     = k1x;  kp[(NK + k) * 2 + 1]     = k1y;
    kp[(2 * NK + k) * 2 + 0] = k2x;  kp[(2 * NK + k) * 2 + 1] = k2y;
}

// Fused: per (stack, b, k) map. Phase A: all 9 float4 NT-loads in flight.
// Phase B: hw-sigmoid in place + split-chain double reduce (no stores).
// Phase C: all 9 NT stores as one clean write burst (better R/W stream
// separation at the memory controller than interleaved load/store).
// Thread 0 decodes keypoints + writes zeta. One block per map.
__global__ __launch_bounds__(256) void fused(
        const float* __restrict__ Rk,
        const float* __restrict__ tfRk,
        float* __restrict__ out) {
    const int blk   = blockIdx.x;
    const int stack = blk >> 10;      // 0: Rk, 1: tf_Rk
    const int pair  = blk & 1023;     // b*64 + k

    const float* __restrict__ src = (stack ? tfRk : Rk) + (size_t)pair * HW;
    const vfloat4* __restrict__ s4 = (const vfloat4*)src;
    vfloat4* __restrict__ d4 =
        (vfloat4*)(out + (size_t)stack * MAP_ELEMS + (size_t)pair * HW);

    const int t = threadIdx.x;

    // ---- Phase A: all loads in flight (non-temporal: use-once stream) ----
    vfloat4 v[ITERS];
    #pragma unroll
    for (int i = 0; i < ITERS; ++i)
        v[i] = __builtin_nontemporal_load(&s4[t + i * 256]);

    // ---- Phase B: sigmoid in place + double reduce (2-way split chains) ----
    double z0 = 0.0, z1 = 0.0;
    double kx0 = 0.0, kx1 = 0.0;
    double ky0 = 0.0, ky1 = 0.0;
    #pragma unroll
    for (int i = 0; i < ITERS; ++i) {
        const int idx = t + i * 256;
        vfloat4 s;
        s.x = sigf(v[i].x); s.y = sigf(v[i].y);
        s.z = sigf(v[i].z); s.w = sigf(v[i].w);
        v[i] = s;                          // reuse regs; stored in Phase C
        const int fx = idx * 4;            // flat element index
        const int x0 = fx % NW;            // float4 never crosses a row (96%4==0)
        const int y  = fx / NW;
        const double sum4 = (double)s.x + (double)s.y + (double)s.z + (double)s.w;
        const double xterm = sum4 * (double)x0
                           + ((double)s.y + 2.0 * (double)s.z + 3.0 * (double)s.w);
        const double yterm = sum4 * (double)y;
        if (i & 1) { z1 += sum4; kx1 += xterm; ky1 += yterm; }
        else       { z0 += sum4; kx0 += xterm; ky0 += yterm; }
    }
    double zeta = z0 + z1, kx = kx0 + kx1, ky = ky0 + ky1;

    // ---- Phase C: grouped NT store burst ----
    #pragma unroll
    for (int i = 0; i < ITERS; ++i)
        __builtin_nontemporal_store(v[i], &d4[t + i * 256]);

    // wave (64-lane) shuffle reduce, then cross-wave via LDS
    for (int o = 32; o > 0; o >>= 1) {
        zeta += __shfl_down(zeta, o, 64);
        kx   += __shfl_down(kx,   o, 64);
        ky   += __shfl_down(ky,   o, 64);
    }
    __shared__ double sh[3][4];
    const int lane = t & 63, wave = t >> 6;
    if (lane == 0) { sh[0][wave] = zeta; sh[1][wave] = kx; sh[2][wave] = ky; }
    __syncthreads();
    if (t == 0) {
        const double z  = sh[0][0] + sh[0][1] + sh[0][2] + sh[0][3];
        const double xx = sh[1][0] + sh[1][1] + sh[1][2] + sh[1][3];
        const double yy = sh[2][0] + sh[2][1] + sh[2][2] + sh[2][3];

        out[ZETA_BASE + (size_t)stack * PAIRS + pair] = (float)z;

        const int b = pair >> 6, k = pair & 63;
        float* kp = out + KP_BASE + (size_t)stack * KP_STACK + (size_t)b * (3 * NK * 2);
        decode_one(z, xx, yy, src, kp, k);
    }
}

extern "C" void kernel_launch(void* const* d_in, const int* in_sizes, int n_in,
                              void* d_out, int out_size, void* d_ws, size_t ws_size,
                              hipStream_t stream) {
    const float* Rk   = (const float*)d_in[0];
    const float* tfRk = (const float*)d_in[1];
    float* out = (float*)d_out;
    (void)d_ws; (void)ws_size;

    fused<<<2 * PAIRS, 256, 0, stream>>>(Rk, tfRk, out);
}